// Round 6
// baseline (311.556 us; speedup 1.0000x reference)
//
#include <hip/hip_runtime.h>
#include <stdint.h>
#include <math.h>

typedef __attribute__((ext_vector_type(8))) short short8;
typedef __attribute__((ext_vector_type(4))) float float4v;

__device__ __forceinline__ uint16_t f2bf(float f){
  union { float f; uint32_t i; } c; c.f = f;
  uint32_t r = c.i + 0x7fffu + ((c.i >> 16) & 1u);   // round-to-nearest-even
  return (uint16_t)(r >> 16);
}
__device__ __forceinline__ uint32_t pack2(float lo, float hi){
  return (uint32_t)f2bf(lo) | ((uint32_t)f2bf(hi) << 16);
}
__device__ __forceinline__ void acc_bf2(uint32_t w, float& x, float& y){
  union { uint32_t i; float f; } a, b;
  a.i = w << 16; b.i = w & 0xffff0000u;
  x += a.f; y += b.f;
}
__device__ __forceinline__ void accum8(uint4 v, float* a){
  acc_bf2(v.x, a[0], a[1]); acc_bf2(v.y, a[2], a[3]);
  acc_bf2(v.z, a[4], a[5]); acc_bf2(v.w, a[6], a[7]);
}

// ---- prep: fused (bin pass of counting sort) + (fp32->bf16 conversion) -----
// Blocks [0,p1blk): bin edges into 256-node buckets (LDS hist + chunked
// global reservation -> contiguous writes). Blocks [p1blk,...): grid-stride
// convert x and the 6 weight matrices to bf16. Independent work, overlapped.

#define P1_EPT 8   // edges per thread, 512 threads -> 4096-edge tiles

__global__ __launch_bounds__(512) void prep_kernel(
    const int* __restrict__ ei, int E, int NB, int CAP,
    int* __restrict__ fill, int2* __restrict__ bins, int p1blk,
    const float* __restrict__ x,
    const float* __restrict__ w0, const float* __restrict__ w1,
    const float* __restrict__ w2, const float* __restrict__ w3,
    const float* __restrict__ w4, const float* __restrict__ w5,
    uint16_t* __restrict__ xb, uint16_t* __restrict__ wb, int nx){
  if ((int)blockIdx.x < p1blk){
    __shared__ int hist[256], base[256], cur[256];
    int tid = threadIdx.x;
    if (tid < 256){ hist[tid] = 0; cur[tid] = 0; }
    __syncthreads();
    int src[P1_EPT], dst[P1_EPT];
    int e0 = blockIdx.x * (512 * P1_EPT);
    #pragma unroll
    for (int k = 0; k < P1_EPT; ++k){
      int e = e0 + k * 512 + tid;
      bool ok = e < E;
      src[k] = ok ? ei[e] : 0;
      dst[k] = ok ? ei[E + e] : -1;        // sentinel
      if (ok) atomicAdd(&hist[dst[k] >> 8], 1);
    }
    __syncthreads();
    if (tid < NB && hist[tid] > 0) base[tid] = atomicAdd(&fill[tid], hist[tid]);
    __syncthreads();
    #pragma unroll
    for (int k = 0; k < P1_EPT; ++k){
      if (dst[k] >= 0){
        int b = dst[k] >> 8;
        int loc = base[b] + atomicAdd(&cur[b], 1);
        if (loc < CAP) bins[(size_t)b * CAP + loc] = make_int2(src[k], dst[k]);
      }
    }
  } else {
    int i = (blockIdx.x - p1blk) * 512 + threadIdx.x;
    int stride = (gridDim.x - p1blk) * 512;
    for (int j = i; j < nx; j += stride) xb[j] = f2bf(x[j]);
    const int WSZ = 128 * 128;
    for (int j = i; j < 6 * WSZ; j += stride){
      int t = j >> 14, o = j & (WSZ - 1);
      const float* w = t == 0 ? w0 : t == 1 ? w1 : t == 2 ? w2 : t == 3 ? w3 : t == 4 ? w4 : w5;
      wb[j] = f2bf(w[o]);
    }
  }
}

// ---- build: per-bucket CSR (one WG per bucket, LDS hist + scan + scatter) --

__global__ __launch_bounds__(512) void build_kernel(const int2* __restrict__ bins,
                                                    const int* __restrict__ fill,
                                                    int CAP, int n,
                                                    int2* __restrict__ rowptr2,
                                                    int* __restrict__ esrc){
  __shared__ int h[256], s[256], cursor[256];
  int b = blockIdx.x, tid = threadIdx.x;
  int cnt = fill[b]; if (cnt > CAP) cnt = CAP;
  int gbase = b * CAP;
  if (tid < 256) h[tid] = 0;
  __syncthreads();
  for (int i = tid; i < cnt; i += 512)
    atomicAdd(&h[bins[(size_t)gbase + i].y & 255], 1);
  __syncthreads();
  if (tid < 256) s[tid] = h[tid];
  __syncthreads();
  #pragma unroll
  for (int off = 1; off < 256; off <<= 1){
    int v = 0;
    if (tid < 256 && tid >= off) v = s[tid - off];
    __syncthreads();
    if (tid < 256) s[tid] += v;
    __syncthreads();
  }
  if (tid < 256){
    int node = (b << 8) + tid;
    int excl = s[tid] - h[tid];
    if (node < n) rowptr2[node] = make_int2(gbase + excl, gbase + s[tid]);
    cursor[tid] = gbase + excl;
  }
  __syncthreads();
  for (int i = tid; i < cnt; i += 512){
    int2 e = bins[(size_t)gbase + i];
    int p = atomicAdd(&cursor[e.y & 255], 1);
    esrc[p] = e.x;
  }
}

// ---- fused layer kernels ---------------------------------------------------
// Block = 256 threads (4 waves) handles 64 nodes.
// Phase A: gather-mean of neighbor rows (bf16, 16B/lane, 4 edges in parallel
//   per wave, 2-deep unroll) -> LDS tile [64][136] bf16 (pad 8 shorts: both
//   the b128 reads and the 16-lane writes sit at the LDS bank floor).
// Phase B: MFMA 16x16x32 bf16. A0 from LDS tile, A1 = own row from global.
//   Frag layouts (HW-verified): A[m=lane&15][k=quad*8+j], B[k][n=lane&15]
//   from W[col][k], C/D col=lane&15, row=quad*4+reg.

#define TSTRIDE 136

__device__ __forceinline__ void gather_node(const uint4* __restrict__ xv,
                                            const int* __restrict__ esrc,
                                            int beg, int end, int sub, int fq,
                                            float* a){
  int e = beg + sub;
  for (; e + 4 < end; e += 8){
    int s0 = esrc[e], s1 = esrc[e + 4];
    uint4 v0 = xv[(size_t)s0 * 16 + fq];
    uint4 v1 = xv[(size_t)s1 * 16 + fq];
    accum8(v0, a); accum8(v1, a);
  }
  for (; e < end; e += 4){
    uint4 v = xv[(size_t)esrc[e] * 16 + fq];
    accum8(v, a);
  }
}

__device__ __forceinline__ void agg_phase(const uint16_t* __restrict__ xin,
                                          const int2* __restrict__ rowptr2,
                                          const int* __restrict__ esrc,
                                          uint16_t* atile, int nb, int wid,
                                          int lane, int n){
  int sub = lane >> 4, fq = lane & 15;
  const uint4* xv = (const uint4*)xin;
  for (int t = 0; t < 16; ++t){
    int row = wid * 16 + t;
    int node = nb + row;
    float a[8] = {0.f,0.f,0.f,0.f,0.f,0.f,0.f,0.f};
    float inv = 0.f;
    if (node < n){
      int2 be = rowptr2[node];
      inv = 1.f / fmaxf((float)(be.y - be.x), 1.f);
      gather_node(xv, esrc, be.x, be.y, sub, fq, a);
    }
    #pragma unroll
    for (int i = 0; i < 8; ++i){
      a[i] += __shfl_xor(a[i], 16);
      a[i] += __shfl_xor(a[i], 32);
      a[i] *= inv;
    }
    if (sub == 0){
      uint4 o;
      o.x = pack2(a[0], a[1]); o.y = pack2(a[2], a[3]);
      o.z = pack2(a[4], a[5]); o.w = pack2(a[6], a[7]);
      *(uint4*)(atile + row * TSTRIDE + fq * 8) = o;
    }
  }
}

// layer 1: x1 = relu(mean(x_nbr)@W1l^T + b1 + x@W1r^T), bf16 out
__global__ __launch_bounds__(256) void layer1_kernel(
    const uint16_t* __restrict__ xb, const int2* __restrict__ rowptr2,
    const int* __restrict__ esrc,
    const uint16_t* __restrict__ Wl, const uint16_t* __restrict__ Wr,
    const float* __restrict__ bias, uint16_t* __restrict__ x1b, int n){
  __shared__ uint16_t atile[64 * TSTRIDE];
  int lane = threadIdx.x & 63, wid = threadIdx.x >> 6;
  int nb = blockIdx.x * 64;

  agg_phase(xb, rowptr2, esrc, atile, nb, wid, lane, n);
  __syncthreads();

  int m = lane & 15, quad = lane >> 4;
  int arow = nb + wid * 16 + m; if (arow > n - 1) arow = n - 1;
  short8 a0f[4], a1f[4];
  #pragma unroll
  for (int ks = 0; ks < 4; ++ks){
    a0f[ks] = *(const short8*)(atile + (wid * 16 + m) * TSTRIDE + ks * 32 + quad * 8);
    a1f[ks] = *(const short8*)(xb + (size_t)arow * 128 + ks * 32 + quad * 8);
  }
  float4v acc[8];
  #pragma unroll
  for (int ct = 0; ct < 8; ++ct) acc[ct] = (float4v){0.f, 0.f, 0.f, 0.f};
  #pragma unroll
  for (int ks = 0; ks < 4; ++ks){
    #pragma unroll
    for (int ct = 0; ct < 8; ++ct){
      short8 b0 = *(const short8*)(Wl + (size_t)(ct * 16 + m) * 128 + ks * 32 + quad * 8);
      acc[ct] = __builtin_amdgcn_mfma_f32_16x16x32_bf16(a0f[ks], b0, acc[ct], 0, 0, 0);
      short8 b1 = *(const short8*)(Wr + (size_t)(ct * 16 + m) * 128 + ks * 32 + quad * 8);
      acc[ct] = __builtin_amdgcn_mfma_f32_16x16x32_bf16(a1f[ks], b1, acc[ct], 0, 0, 0);
    }
  }
  #pragma unroll
  for (int ct = 0; ct < 8; ++ct){
    int col = ct * 16 + m;
    float bv = bias[col];
    #pragma unroll
    for (int i = 0; i < 4; ++i){
      int grow = nb + wid * 16 + quad * 4 + i;
      if (grow < n)
        x1b[(size_t)grow * 128 + col] = f2bf(fmaxf(acc[ct][i] + bv, 0.f));
    }
  }
}

// layers 2+3: one agg of x1, two GEMMs, both output halves (fp32)
__global__ __launch_bounds__(256) void layer23_kernel(
    const uint16_t* __restrict__ x1b, const int2* __restrict__ rowptr2,
    const int* __restrict__ esrc,
    const uint16_t* __restrict__ W2l, const uint16_t* __restrict__ W2r,
    const float* __restrict__ b2,
    const uint16_t* __restrict__ W3l, const uint16_t* __restrict__ W3r,
    const float* __restrict__ b3,
    float* __restrict__ out, size_t half, int n){
  __shared__ uint16_t atile[64 * TSTRIDE];
  int lane = threadIdx.x & 63, wid = threadIdx.x >> 6;
  int nb = blockIdx.x * 64;

  agg_phase(x1b, rowptr2, esrc, atile, nb, wid, lane, n);
  __syncthreads();

  int m = lane & 15, quad = lane >> 4;
  int arow = nb + wid * 16 + m; if (arow > n - 1) arow = n - 1;
  short8 a0f[4], a1f[4];
  #pragma unroll
  for (int ks = 0; ks < 4; ++ks){
    a0f[ks] = *(const short8*)(atile + (wid * 16 + m) * TSTRIDE + ks * 32 + quad * 8);
    a1f[ks] = *(const short8*)(x1b + (size_t)arow * 128 + ks * 32 + quad * 8);
  }
  #pragma unroll
  for (int pass = 0; pass < 2; ++pass){
    const uint16_t* Wl = pass ? W3l : W2l;
    const uint16_t* Wr = pass ? W3r : W2r;
    const float*    bb = pass ? b3  : b2;
    float* op = out + (pass ? half : 0);
    float4v acc[8];
    #pragma unroll
    for (int ct = 0; ct < 8; ++ct) acc[ct] = (float4v){0.f, 0.f, 0.f, 0.f};
    #pragma unroll
    for (int ks = 0; ks < 4; ++ks){
      #pragma unroll
      for (int ct = 0; ct < 8; ++ct){
        short8 b0 = *(const short8*)(Wl + (size_t)(ct * 16 + m) * 128 + ks * 32 + quad * 8);
        acc[ct] = __builtin_amdgcn_mfma_f32_16x16x32_bf16(a0f[ks], b0, acc[ct], 0, 0, 0);
        short8 b1 = *(const short8*)(Wr + (size_t)(ct * 16 + m) * 128 + ks * 32 + quad * 8);
        acc[ct] = __builtin_amdgcn_mfma_f32_16x16x32_bf16(a1f[ks], b1, acc[ct], 0, 0, 0);
      }
    }
    #pragma unroll
    for (int ct = 0; ct < 8; ++ct){
      int col = ct * 16 + m;
      float bv = bb[col];
      #pragma unroll
      for (int i = 0; i < 4; ++i){
        int grow = nb + wid * 16 + quad * 4 + i;
        if (grow < n) op[(size_t)grow * 128 + col] = acc[ct][i] + bv;
      }
    }
  }
}

// ---- launcher --------------------------------------------------------------

extern "C" void kernel_launch(void* const* d_in, const int* in_sizes, int n_in,
                              void* d_out, int out_size, void* d_ws, size_t ws_size,
                              hipStream_t stream) {
  const float* x   = (const float*)d_in[0];   // fp32 [N,128]
  const int*   ei  = (const int*)d_in[1];     // int32 [2,E]
  const float* W1l = (const float*)d_in[2];
  const float* b1l = (const float*)d_in[3];
  const float* W1r = (const float*)d_in[4];
  const float* W2l = (const float*)d_in[5];
  const float* b2l = (const float*)d_in[6];
  const float* W2r = (const float*)d_in[7];
  const float* W3l = (const float*)d_in[8];
  const float* b3l = (const float*)d_in[9];
  const float* W3r = (const float*)d_in[10];
  float* out = (float*)d_out;

  const int n = in_sizes[0] / 128;
  const int E = in_sizes[1] / 2;
  const size_t half = (size_t)n * 128;        // elements per output half
  const int WSZ = 128 * 128;

  const int NB = (n + 255) >> 8;              // 256-node buckets (n <= 65536)
  int mean = (E + NB - 1) / NB;
  int CAP = mean + 8 * (int)sqrt((double)mean) + 64;
  CAP = (CAP + 63) & ~63;                     // per-bucket capacity w/ 8-sigma slack

  size_t off = 0;
  auto carve = [&](size_t bytes) -> void* {
    void* p = (char*)d_ws + off;
    off += (bytes + 255) & ~(size_t)255;
    return p;
  };
  int2*     rowptr2 = (int2*)carve((size_t)n * 8);
  int*      fill    = (int*)carve((size_t)NB * 4);
  int*      esrc    = (int*)carve((size_t)NB * CAP * 4);
  uint16_t* xb      = (uint16_t*)carve(half * 2);            // bf16 copy of x
  uint16_t* wb      = (uint16_t*)carve((size_t)6 * WSZ * 2); // bf16 weights
  uint16_t* x1b     = (uint16_t*)carve(half * 2);            // bf16 x1
  int2*     bins    = (int2*)carve((size_t)NB * CAP * 8);    // pass-1 staging
  (void)ws_size;  // measured ws_size = 256 MiB >> ~45 MB used

  hipMemsetAsync(fill, 0, (size_t)NB * 4, stream);

  int p1blk = (E + 512 * P1_EPT - 1) / (512 * P1_EPT);
  int cblk  = 256;                            // conversion blocks (grid-stride)
  prep_kernel<<<p1blk + cblk, 512, 0, stream>>>(ei, E, NB, CAP, fill, bins, p1blk,
                                                x, W1l, W1r, W2l, W2r, W3l, W3r,
                                                xb, wb, (int)half);
  build_kernel<<<NB, 512, 0, stream>>>(bins, fill, CAP, n, rowptr2, esrc);

  int lblk = (n + 63) / 64;
  const uint16_t *Wb1l = wb, *Wb1r = wb + WSZ, *Wb2l = wb + 2 * WSZ,
                 *Wb2r = wb + 3 * WSZ, *Wb3l = wb + 4 * WSZ, *Wb3r = wb + 5 * WSZ;

  layer1_kernel<<<lblk, 256, 0, stream>>>(xb, rowptr2, esrc, Wb1l, Wb1r, b1l, x1b, n);
  layer23_kernel<<<lblk, 256, 0, stream>>>(x1b, rowptr2, esrc,
                                           Wb2l, Wb2r, b2l, Wb3l, Wb3r, b3l,
                                           out, half, n);
}

// Round 7
// 289.282 us; speedup vs baseline: 1.0770x; 1.0770x over previous
//
#include <hip/hip_runtime.h>
#include <stdint.h>
#include <math.h>

typedef __attribute__((ext_vector_type(8))) short short8;
typedef __attribute__((ext_vector_type(4))) float float4v;

__device__ __forceinline__ uint16_t f2bf(float f){
  union { float f; uint32_t i; } c; c.f = f;
  uint32_t r = c.i + 0x7fffu + ((c.i >> 16) & 1u);   // round-to-nearest-even
  return (uint16_t)(r >> 16);
}
__device__ __forceinline__ uint32_t pack2(float lo, float hi){
  return (uint32_t)f2bf(lo) | ((uint32_t)f2bf(hi) << 16);
}
__device__ __forceinline__ void acc_bf2(uint32_t w, float& x, float& y){
  union { uint32_t i; float f; } a, b;
  a.i = w << 16; b.i = w & 0xffff0000u;
  x += a.f; y += b.f;
}
__device__ __forceinline__ void accum8(uint4 v, float* a){
  acc_bf2(v.x, a[0], a[1]); acc_bf2(v.y, a[2], a[3]);
  acc_bf2(v.z, a[4], a[5]); acc_bf2(v.w, a[6], a[7]);
}

// ---- prep: fused (bin pass of counting sort) + (fp32->bf16 conversion) -----
// Blocks [0,p1blk): bin edges into 256-node buckets (LDS hist + chunked
// global reservation -> contiguous full-line writes). Blocks [p1blk,...):
// grid-stride convert x and the 6 weight matrices to bf16. Overlapped.

#define P1_EPT 8   // edges per thread, 512 threads -> 4096-edge tiles

__global__ __launch_bounds__(512) void prep_kernel(
    const int* __restrict__ ei, int E, int NB, int CAP,
    int* __restrict__ fill, int2* __restrict__ bins, int p1blk,
    const float* __restrict__ x,
    const float* __restrict__ w0, const float* __restrict__ w1,
    const float* __restrict__ w2, const float* __restrict__ w3,
    const float* __restrict__ w4, const float* __restrict__ w5,
    uint16_t* __restrict__ xb, uint16_t* __restrict__ wb, int nx){
  if ((int)blockIdx.x < p1blk){
    __shared__ int hist[256], base[256], cur[256];
    int tid = threadIdx.x;
    if (tid < 256){ hist[tid] = 0; cur[tid] = 0; }
    __syncthreads();
    int src[P1_EPT], dst[P1_EPT];
    int e0 = blockIdx.x * (512 * P1_EPT);
    #pragma unroll
    for (int k = 0; k < P1_EPT; ++k){
      int e = e0 + k * 512 + tid;
      bool ok = e < E;
      src[k] = ok ? ei[e] : 0;
      dst[k] = ok ? ei[E + e] : -1;        // sentinel
      if (ok) atomicAdd(&hist[dst[k] >> 8], 1);
    }
    __syncthreads();
    if (tid < NB && hist[tid] > 0) base[tid] = atomicAdd(&fill[tid], hist[tid]);
    __syncthreads();
    #pragma unroll
    for (int k = 0; k < P1_EPT; ++k){
      if (dst[k] >= 0){
        int b = dst[k] >> 8;
        int loc = base[b] + atomicAdd(&cur[b], 1);
        if (loc < CAP) bins[(size_t)b * CAP + loc] = make_int2(src[k], dst[k]);
      }
    }
  } else {
    int i = (blockIdx.x - p1blk) * 512 + threadIdx.x;
    int stride = (gridDim.x - p1blk) * 512;
    for (int j = i; j < nx; j += stride) xb[j] = f2bf(x[j]);
    const int WSZ = 128 * 128;
    for (int j = i; j < 6 * WSZ; j += stride){
      int t = j >> 14, o = j & (WSZ - 1);
      const float* w = t == 0 ? w0 : t == 1 ? w1 : t == 2 ? w2 : t == 3 ? w3 : t == 4 ? w4 : w5;
      wb[j] = f2bf(w[o]);
    }
  }
}

// ---- build: per-bucket CSR (one WG per bucket, LDS hist + scan + scatter) --

__global__ __launch_bounds__(512) void build_kernel(const int2* __restrict__ bins,
                                                    const int* __restrict__ fill,
                                                    int CAP, int n,
                                                    int2* __restrict__ rowptr2,
                                                    int* __restrict__ esrc){
  __shared__ int h[256], s[256], cursor[256];
  int b = blockIdx.x, tid = threadIdx.x;
  int cnt = fill[b]; if (cnt > CAP) cnt = CAP;
  int gbase = b * CAP;
  if (tid < 256) h[tid] = 0;
  __syncthreads();
  for (int i = tid; i < cnt; i += 512)
    atomicAdd(&h[bins[(size_t)gbase + i].y & 255], 1);
  __syncthreads();
  if (tid < 256) s[tid] = h[tid];
  __syncthreads();
  #pragma unroll
  for (int off = 1; off < 256; off <<= 1){
    int v = 0;
    if (tid < 256 && tid >= off) v = s[tid - off];
    __syncthreads();
    if (tid < 256) s[tid] += v;
    __syncthreads();
  }
  if (tid < 256){
    int node = (b << 8) + tid;
    int excl = s[tid] - h[tid];
    if (node < n) rowptr2[node] = make_int2(gbase + excl, gbase + s[tid]);
    cursor[tid] = gbase + excl;
  }
  __syncthreads();
  for (int i = tid; i < cnt; i += 512){
    int2 e = bins[(size_t)gbase + i];
    int p = atomicAdd(&cursor[e.y & 255], 1);
    esrc[p] = e.x;
  }
}

// ---- mean aggregation: one wave per NODE (max wave-level latency hiding) ---
// bf16 rows (256B): 16B/lane, 16 lanes/row, 4 edges in parallel x 2-deep
// unroll = 8 independent row-gathers in flight per wave. Output bf16.

__global__ __launch_bounds__(256) void agg_kernel(const uint16_t* __restrict__ xin,
                                                  const int2* __restrict__ rowptr2,
                                                  const int* __restrict__ esrc,
                                                  uint16_t* __restrict__ aggw, int n){
  int node = blockIdx.x * 4 + (threadIdx.x >> 6);
  if (node >= n) return;
  int lane = threadIdx.x & 63;
  int sub = lane >> 4, fq = lane & 15;
  const uint4* xv = (const uint4*)xin;              // row = 16 x uint4
  int2 be = rowptr2[node];
  int beg = be.x, end = be.y;
  float inv = 1.f / fmaxf((float)(end - beg), 1.f);
  float a[8] = {0.f,0.f,0.f,0.f,0.f,0.f,0.f,0.f};
  int e = beg + sub;
  for (; e + 4 < end; e += 8){
    int s0 = esrc[e], s1 = esrc[e + 4];
    uint4 v0 = xv[(size_t)s0 * 16 + fq];
    uint4 v1 = xv[(size_t)s1 * 16 + fq];
    accum8(v0, a); accum8(v1, a);
  }
  for (; e < end; e += 4){
    uint4 v = xv[(size_t)esrc[e] * 16 + fq];
    accum8(v, a);
  }
  #pragma unroll
  for (int i = 0; i < 8; ++i){
    a[i] += __shfl_xor(a[i], 16);
    a[i] += __shfl_xor(a[i], 32);
    a[i] *= inv;
  }
  if (sub == 0){
    uint4 o;
    o.x = pack2(a[0], a[1]); o.y = pack2(a[2], a[3]);
    o.z = pack2(a[4], a[5]); o.w = pack2(a[6], a[7]);
    ((uint4*)aggw)[(size_t)node * 16 + fq] = o;
  }
}

// ---- GEMM kernels ----------------------------------------------------------
// MFMA 16x16x32 bf16, HW-verified layouts: A[m=lane&15][k=quad*8+j];
// B[k][n=lane&15] taken from W[col][k]; C/D col=lane&15, row=quad*4+reg.
// Wave computes 16 rows x 128 cols, K=256 (agg || xin).

// layer 1: x1 = relu(agg@W1l^T + b1 + x@W1r^T), bf16 out
__global__ __launch_bounds__(256) void gemm1_kernel(
    const uint16_t* __restrict__ Aagg, const uint16_t* __restrict__ Ax,
    const uint16_t* __restrict__ Wl, const uint16_t* __restrict__ Wr,
    const float* __restrict__ bias, uint16_t* __restrict__ x1b, int n){
  int lane = threadIdx.x & 63, wid = threadIdx.x >> 6;
  int m = lane & 15, quad = lane >> 4;
  int r0 = blockIdx.x * 64 + wid * 16;
  int arow = r0 + m; if (arow > n - 1) arow = n - 1;   // clamp tail reads
  float4v acc[8];
  #pragma unroll
  for (int ct = 0; ct < 8; ++ct) acc[ct] = (float4v){0.f, 0.f, 0.f, 0.f};
  #pragma unroll
  for (int ks = 0; ks < 4; ++ks){
    short8 a0 = *(const short8*)(Aagg + (size_t)arow * 128 + ks * 32 + quad * 8);
    short8 a1 = *(const short8*)(Ax   + (size_t)arow * 128 + ks * 32 + quad * 8);
    #pragma unroll
    for (int ct = 0; ct < 8; ++ct){
      short8 b0 = *(const short8*)(Wl + (size_t)(ct * 16 + m) * 128 + ks * 32 + quad * 8);
      acc[ct] = __builtin_amdgcn_mfma_f32_16x16x32_bf16(a0, b0, acc[ct], 0, 0, 0);
      short8 b1 = *(const short8*)(Wr + (size_t)(ct * 16 + m) * 128 + ks * 32 + quad * 8);
      acc[ct] = __builtin_amdgcn_mfma_f32_16x16x32_bf16(a1, b1, acc[ct], 0, 0, 0);
    }
  }
  #pragma unroll
  for (int ct = 0; ct < 8; ++ct){
    int col = ct * 16 + m;
    float bv = bias[col];
    #pragma unroll
    for (int i = 0; i < 4; ++i){
      int grow = r0 + quad * 4 + i;
      if (grow < n)
        x1b[(size_t)grow * 128 + col] = f2bf(fmaxf(acc[ct][i] + bv, 0.f));
    }
  }
}

// layers 2+3 merged: A-fragments (agg || x1) loaded once, two weight passes,
// both fp32 output halves written.
__global__ __launch_bounds__(256) void gemm23_kernel(
    const uint16_t* __restrict__ Aagg, const uint16_t* __restrict__ Ax,
    const uint16_t* __restrict__ W2l, const uint16_t* __restrict__ W2r,
    const float* __restrict__ b2,
    const uint16_t* __restrict__ W3l, const uint16_t* __restrict__ W3r,
    const float* __restrict__ b3,
    float* __restrict__ out, size_t half, int n){
  int lane = threadIdx.x & 63, wid = threadIdx.x >> 6;
  int m = lane & 15, quad = lane >> 4;
  int r0 = blockIdx.x * 64 + wid * 16;
  int arow = r0 + m; if (arow > n - 1) arow = n - 1;
  short8 a0f[4], a1f[4];
  #pragma unroll
  for (int ks = 0; ks < 4; ++ks){
    a0f[ks] = *(const short8*)(Aagg + (size_t)arow * 128 + ks * 32 + quad * 8);
    a1f[ks] = *(const short8*)(Ax   + (size_t)arow * 128 + ks * 32 + quad * 8);
  }
  #pragma unroll
  for (int pass = 0; pass < 2; ++pass){
    const uint16_t* Wl = pass ? W3l : W2l;
    const uint16_t* Wr = pass ? W3r : W2r;
    const float*    bb = pass ? b3  : b2;
    float* op = out + (pass ? half : 0);
    float4v acc[8];
    #pragma unroll
    for (int ct = 0; ct < 8; ++ct) acc[ct] = (float4v){0.f, 0.f, 0.f, 0.f};
    #pragma unroll
    for (int ks = 0; ks < 4; ++ks){
      #pragma unroll
      for (int ct = 0; ct < 8; ++ct){
        short8 b0 = *(const short8*)(Wl + (size_t)(ct * 16 + m) * 128 + ks * 32 + quad * 8);
        acc[ct] = __builtin_amdgcn_mfma_f32_16x16x32_bf16(a0f[ks], b0, acc[ct], 0, 0, 0);
        short8 b1 = *(const short8*)(Wr + (size_t)(ct * 16 + m) * 128 + ks * 32 + quad * 8);
        acc[ct] = __builtin_amdgcn_mfma_f32_16x16x32_bf16(a1f[ks], b1, acc[ct], 0, 0, 0);
      }
    }
    #pragma unroll
    for (int ct = 0; ct < 8; ++ct){
      int col = ct * 16 + m;
      float bv = bb[col];
      #pragma unroll
      for (int i = 0; i < 4; ++i){
        int grow = r0 + quad * 4 + i;
        if (grow < n) op[(size_t)grow * 128 + col] = acc[ct][i] + bv;
      }
    }
  }
}

// ---- launcher --------------------------------------------------------------

extern "C" void kernel_launch(void* const* d_in, const int* in_sizes, int n_in,
                              void* d_out, int out_size, void* d_ws, size_t ws_size,
                              hipStream_t stream) {
  const float* x   = (const float*)d_in[0];   // fp32 [N,128]
  const int*   ei  = (const int*)d_in[1];     // int32 [2,E]
  const float* W1l = (const float*)d_in[2];
  const float* b1l = (const float*)d_in[3];
  const float* W1r = (const float*)d_in[4];
  const float* W2l = (const float*)d_in[5];
  const float* b2l = (const float*)d_in[6];
  const float* W2r = (const float*)d_in[7];
  const float* W3l = (const float*)d_in[8];
  const float* b3l = (const float*)d_in[9];
  const float* W3r = (const float*)d_in[10];
  float* out = (float*)d_out;

  const int n = in_sizes[0] / 128;
  const int E = in_sizes[1] / 2;
  const size_t half = (size_t)n * 128;        // elements per output half
  const int WSZ = 128 * 128;

  const int NB = (n + 255) >> 8;              // 256-node buckets (n <= 65536)
  int mean = (E + NB - 1) / NB;
  int CAP = mean + 8 * (int)sqrt((double)mean) + 64;
  CAP = (CAP + 63) & ~63;                     // per-bucket capacity, 8-sigma slack

  size_t off = 0;
  auto carve = [&](size_t bytes) -> void* {
    void* p = (char*)d_ws + off;
    off += (bytes + 255) & ~(size_t)255;
    return p;
  };
  int2*     rowptr2 = (int2*)carve((size_t)n * 8);
  int*      fill    = (int*)carve((size_t)NB * 4);
  int*      esrc    = (int*)carve((size_t)NB * CAP * 4);
  uint16_t* xb      = (uint16_t*)carve(half * 2);            // bf16 copy of x
  uint16_t* wb      = (uint16_t*)carve((size_t)6 * WSZ * 2); // bf16 weights
  uint16_t* x1b     = (uint16_t*)carve(half * 2);            // bf16 x1
  uint16_t* agg     = (uint16_t*)carve(half * 2);            // bf16 agg
  int2*     bins    = (int2*)carve((size_t)NB * CAP * 8);    // pass-1 staging
  (void)ws_size;  // measured ws_size = 256 MiB >> ~50 MB used

  hipMemsetAsync(fill, 0, (size_t)NB * 4, stream);

  int p1blk = (E + 512 * P1_EPT - 1) / (512 * P1_EPT);
  int cblk  = 256;                            // conversion blocks (grid-stride)
  prep_kernel<<<p1blk + cblk, 512, 0, stream>>>(ei, E, NB, CAP, fill, bins, p1blk,
                                                x, W1l, W1r, W2l, W2r, W3l, W3r,
                                                xb, wb, (int)half);
  build_kernel<<<NB, 512, 0, stream>>>(bins, fill, CAP, n, rowptr2, esrc);

  int ablk = (n + 3) / 4;
  int gblk = (n + 63) / 64;
  const uint16_t *Wb1l = wb, *Wb1r = wb + WSZ, *Wb2l = wb + 2 * WSZ,
                 *Wb2r = wb + 3 * WSZ, *Wb3l = wb + 4 * WSZ, *Wb3r = wb + 5 * WSZ;

  // layer 1
  agg_kernel<<<ablk, 256, 0, stream>>>(xb, rowptr2, esrc, agg, n);
  gemm1_kernel<<<gblk, 256, 0, stream>>>(agg, xb, Wb1l, Wb1r, b1l, x1b, n);

  // shared aggregation of x1, then layers 2+3 in one merged GEMM kernel
  agg_kernel<<<ablk, 256, 0, stream>>>(x1b, rowptr2, esrc, agg, n);
  gemm23_kernel<<<gblk, 256, 0, stream>>>(agg, x1b, Wb2l, Wb2r, b2l,
                                          Wb3l, Wb3r, b3l, out, half, n);
}

// Round 8
// 233.471 us; speedup vs baseline: 1.3345x; 1.2391x over previous
//
#include <hip/hip_runtime.h>
#include <stdint.h>
#include <math.h>

typedef __attribute__((ext_vector_type(8))) short short8;
typedef __attribute__((ext_vector_type(4))) float float4v;

__device__ __forceinline__ uint16_t f2bf(float f){
  union { float f; uint32_t i; } c; c.f = f;
  uint32_t r = c.i + 0x7fffu + ((c.i >> 16) & 1u);   // round-to-nearest-even
  return (uint16_t)(r >> 16);
}
__device__ __forceinline__ uint32_t pack2(float lo, float hi){
  return (uint32_t)f2bf(lo) | ((uint32_t)f2bf(hi) << 16);
}
__device__ __forceinline__ void acc_bf2(uint32_t w, float& x, float& y){
  union { uint32_t i; float f; } a, b;
  a.i = w << 16; b.i = w & 0xffff0000u;
  x += a.f; y += b.f;
}
__device__ __forceinline__ void accum8(uint4 v, float* a){
  acc_bf2(v.x, a[0], a[1]); acc_bf2(v.y, a[2], a[3]);
  acc_bf2(v.z, a[4], a[5]); acc_bf2(v.w, a[6], a[7]);
}

// ---- prep: fused (bin pass of counting sort) + (fp32->bf16 conversion) -----

#define P1_EPT 8   // edges per thread, 512 threads -> 4096-edge tiles

__global__ __launch_bounds__(512) void prep_kernel(
    const int* __restrict__ ei, int E, int NB, int CAP,
    int* __restrict__ fill, int2* __restrict__ bins, int p1blk,
    const float* __restrict__ x,
    const float* __restrict__ w0, const float* __restrict__ w1,
    const float* __restrict__ w2, const float* __restrict__ w3,
    const float* __restrict__ w4, const float* __restrict__ w5,
    uint16_t* __restrict__ xb, uint16_t* __restrict__ wb, int nx){
  if ((int)blockIdx.x < p1blk){
    __shared__ int hist[256], base[256], cur[256];
    int tid = threadIdx.x;
    if (tid < 256){ hist[tid] = 0; cur[tid] = 0; }
    __syncthreads();
    int src[P1_EPT], dst[P1_EPT];
    int e0 = blockIdx.x * (512 * P1_EPT);
    #pragma unroll
    for (int k = 0; k < P1_EPT; ++k){
      int e = e0 + k * 512 + tid;
      bool ok = e < E;
      src[k] = ok ? ei[e] : 0;
      dst[k] = ok ? ei[E + e] : -1;        // sentinel
      if (ok) atomicAdd(&hist[dst[k] >> 8], 1);
    }
    __syncthreads();
    if (tid < NB && hist[tid] > 0) base[tid] = atomicAdd(&fill[tid], hist[tid]);
    __syncthreads();
    #pragma unroll
    for (int k = 0; k < P1_EPT; ++k){
      if (dst[k] >= 0){
        int b = dst[k] >> 8;
        int loc = base[b] + atomicAdd(&cur[b], 1);
        if (loc < CAP) bins[(size_t)b * CAP + loc] = make_int2(src[k], dst[k]);
      }
    }
  } else {
    int i = (blockIdx.x - p1blk) * 512 + threadIdx.x;
    int stride = (gridDim.x - p1blk) * 512;
    for (int j = i; j < nx; j += stride) xb[j] = f2bf(x[j]);
    const int WSZ = 128 * 128;
    for (int j = i; j < 6 * WSZ; j += stride){
      int t = j >> 14, o = j & (WSZ - 1);
      const float* w = t == 0 ? w0 : t == 1 ? w1 : t == 2 ? w2 : t == 3 ? w3 : t == 4 ? w4 : w5;
      wb[j] = f2bf(w[o]);
    }
  }
}

// ---- build: per-bucket CSR (one WG per bucket, LDS hist + scan + scatter) --

__global__ __launch_bounds__(512) void build_kernel(const int2* __restrict__ bins,
                                                    const int* __restrict__ fill,
                                                    int CAP, int n,
                                                    int2* __restrict__ rowptr2,
                                                    int* __restrict__ esrc){
  __shared__ int h[256], s[256], cursor[256];
  int b = blockIdx.x, tid = threadIdx.x;
  int cnt = fill[b]; if (cnt > CAP) cnt = CAP;
  int gbase = b * CAP;
  if (tid < 256) h[tid] = 0;
  __syncthreads();
  for (int i = tid; i < cnt; i += 512)
    atomicAdd(&h[bins[(size_t)gbase + i].y & 255], 1);
  __syncthreads();
  if (tid < 256) s[tid] = h[tid];
  __syncthreads();
  #pragma unroll
  for (int off = 1; off < 256; off <<= 1){
    int v = 0;
    if (tid < 256 && tid >= off) v = s[tid - off];
    __syncthreads();
    if (tid < 256) s[tid] += v;
    __syncthreads();
  }
  if (tid < 256){
    int node = (b << 8) + tid;
    int excl = s[tid] - h[tid];
    if (node < n) rowptr2[node] = make_int2(gbase + excl, gbase + s[tid]);
    cursor[tid] = gbase + excl;
  }
  __syncthreads();
  for (int i = tid; i < cnt; i += 512){
    int2 e = bins[(size_t)gbase + i];
    int p = atomicAdd(&cursor[e.y & 255], 1);
    esrc[p] = e.x;
  }
}

// ---- mean aggregation: one wave per NODE, 16 row-gathers in flight ---------
// bf16 rows (256B): 16B/lane, 16 lanes/row, 4 edges x 4-deep unroll.

__global__ __launch_bounds__(256) void agg_kernel(const uint16_t* __restrict__ xin,
                                                  const int2* __restrict__ rowptr2,
                                                  const int* __restrict__ esrc,
                                                  uint16_t* __restrict__ aggw, int n){
  int node = blockIdx.x * 4 + (threadIdx.x >> 6);
  if (node >= n) return;
  int lane = threadIdx.x & 63;
  int sub = lane >> 4, fq = lane & 15;
  const uint4* xv = (const uint4*)xin;              // row = 16 x uint4
  int2 be = rowptr2[node];
  int beg = be.x, end = be.y;
  float inv = 1.f / fmaxf((float)(end - beg), 1.f);
  float a[8] = {0.f,0.f,0.f,0.f,0.f,0.f,0.f,0.f};
  int e = beg + sub;
  for (; e + 12 < end; e += 16){
    int s0 = esrc[e], s1 = esrc[e + 4], s2 = esrc[e + 8], s3 = esrc[e + 12];
    uint4 v0 = xv[(size_t)s0 * 16 + fq];
    uint4 v1 = xv[(size_t)s1 * 16 + fq];
    uint4 v2 = xv[(size_t)s2 * 16 + fq];
    uint4 v3 = xv[(size_t)s3 * 16 + fq];
    accum8(v0, a); accum8(v1, a); accum8(v2, a); accum8(v3, a);
  }
  for (; e < end; e += 4){
    uint4 v = xv[(size_t)esrc[e] * 16 + fq];
    accum8(v, a);
  }
  #pragma unroll
  for (int i = 0; i < 8; ++i){
    a[i] += __shfl_xor(a[i], 16);
    a[i] += __shfl_xor(a[i], 32);
    a[i] *= inv;
  }
  if (sub == 0){
    uint4 o;
    o.x = pack2(a[0], a[1]); o.y = pack2(a[2], a[3]);
    o.z = pack2(a[4], a[5]); o.w = pack2(a[6], a[7]);
    ((uint4*)aggw)[(size_t)node * 16 + fq] = o;
  }
}

// ---- weight-staged GEMM tiles ----------------------------------------------
// Block = 256 thr (4 waves) computes 64 rows x 64 cols of one pass.
// blockIdx.y selects (colhalf, pass). Stage Wl/Wr 64-col slices (64x128 bf16
// each) into LDS, padded stride 136 shorts -> ds_read_b128 at 2-way (free).
// MFMA 16x16x32 bf16, HW-verified layouts: A[m=lane&15][k=quad*8+j];
// B[k][n=lane&15] from W[col][k]; C/D col=lane&15, row=quad*4+reg.

#define WT_STRIDE 136   // shorts per staged weight row (128 + 8 pad)

__device__ __forceinline__ void stage_weights(const uint16_t* __restrict__ Wl,
                                              const uint16_t* __restrict__ Wr,
                                              int ch, uint16_t* lds_l,
                                              uint16_t* lds_r, int tid){
  const uint4* srcL = (const uint4*)(Wl + (size_t)(ch * 64) * 128);
  const uint4* srcR = (const uint4*)(Wr + (size_t)(ch * 64) * 128);
  #pragma unroll
  for (int i = 0; i < 4; ++i){          // 1024 uint4 per matrix / 256 thr
    int j = tid + i * 256;
    int row = j >> 4, c8 = j & 15;      // 16 uint4 per 128-col row
    uint4 vl = srcL[j], vr = srcR[j];
    *(uint4*)(lds_l + row * WT_STRIDE + c8 * 8) = vl;
    *(uint4*)(lds_r + row * WT_STRIDE + c8 * 8) = vr;
  }
}

// layer 1: x1 = relu(agg@W1l^T + b1 + x@W1r^T), bf16 out. y = colhalf.
__global__ __launch_bounds__(256) void gemm1_kernel(
    const uint16_t* __restrict__ Aagg, const uint16_t* __restrict__ Ax,
    const uint16_t* __restrict__ Wl, const uint16_t* __restrict__ Wr,
    const float* __restrict__ bias, uint16_t* __restrict__ x1b, int n){
  __shared__ uint16_t lds_l[64 * WT_STRIDE], lds_r[64 * WT_STRIDE];
  int tid = threadIdx.x, lane = tid & 63, wid = tid >> 6;
  int m = lane & 15, quad = lane >> 4;
  int ch = blockIdx.y;
  int r0 = blockIdx.x * 64 + wid * 16;
  int arow = r0 + m; if (arow > n - 1) arow = n - 1;   // clamp tail reads

  // A-fragments from global (issued before staging so they overlap)
  short8 a0f[4], a1f[4];
  #pragma unroll
  for (int ks = 0; ks < 4; ++ks){
    a0f[ks] = *(const short8*)(Aagg + (size_t)arow * 128 + ks * 32 + quad * 8);
    a1f[ks] = *(const short8*)(Ax   + (size_t)arow * 128 + ks * 32 + quad * 8);
  }
  stage_weights(Wl, Wr, ch, lds_l, lds_r, tid);
  __syncthreads();

  float4v acc[4];
  #pragma unroll
  for (int ct = 0; ct < 4; ++ct) acc[ct] = (float4v){0.f, 0.f, 0.f, 0.f};
  #pragma unroll
  for (int ks = 0; ks < 4; ++ks){
    #pragma unroll
    for (int ct = 0; ct < 4; ++ct){
      short8 b0 = *(const short8*)(lds_l + (ct * 16 + m) * WT_STRIDE + ks * 32 + quad * 8);
      acc[ct] = __builtin_amdgcn_mfma_f32_16x16x32_bf16(a0f[ks], b0, acc[ct], 0, 0, 0);
      short8 b1 = *(const short8*)(lds_r + (ct * 16 + m) * WT_STRIDE + ks * 32 + quad * 8);
      acc[ct] = __builtin_amdgcn_mfma_f32_16x16x32_bf16(a1f[ks], b1, acc[ct], 0, 0, 0);
    }
  }
  #pragma unroll
  for (int ct = 0; ct < 4; ++ct){
    int col = ch * 64 + ct * 16 + m;
    float bv = bias[col];
    #pragma unroll
    for (int i = 0; i < 4; ++i){
      int grow = r0 + quad * 4 + i;
      if (grow < n)
        x1b[(size_t)grow * 128 + col] = f2bf(fmaxf(acc[ct][i] + bv, 0.f));
    }
  }
}

// layers 2+3: y = (pass<<1)|colhalf; fp32 out halves.
__global__ __launch_bounds__(256) void gemm23_kernel(
    const uint16_t* __restrict__ Aagg, const uint16_t* __restrict__ Ax,
    const uint16_t* __restrict__ W2l, const uint16_t* __restrict__ W2r,
    const float* __restrict__ b2,
    const uint16_t* __restrict__ W3l, const uint16_t* __restrict__ W3r,
    const float* __restrict__ b3,
    float* __restrict__ out, size_t half, int n){
  __shared__ uint16_t lds_l[64 * WT_STRIDE], lds_r[64 * WT_STRIDE];
  int tid = threadIdx.x, lane = tid & 63, wid = tid >> 6;
  int m = lane & 15, quad = lane >> 4;
  int ch = blockIdx.y & 1, pass = blockIdx.y >> 1;
  const uint16_t* Wl = pass ? W3l : W2l;
  const uint16_t* Wr = pass ? W3r : W2r;
  const float*    bb = pass ? b3  : b2;
  float* op = out + (pass ? half : 0);
  int r0 = blockIdx.x * 64 + wid * 16;
  int arow = r0 + m; if (arow > n - 1) arow = n - 1;

  short8 a0f[4], a1f[4];
  #pragma unroll
  for (int ks = 0; ks < 4; ++ks){
    a0f[ks] = *(const short8*)(Aagg + (size_t)arow * 128 + ks * 32 + quad * 8);
    a1f[ks] = *(const short8*)(Ax   + (size_t)arow * 128 + ks * 32 + quad * 8);
  }
  stage_weights(Wl, Wr, ch, lds_l, lds_r, tid);
  __syncthreads();

  float4v acc[4];
  #pragma unroll
  for (int ct = 0; ct < 4; ++ct) acc[ct] = (float4v){0.f, 0.f, 0.f, 0.f};
  #pragma unroll
  for (int ks = 0; ks < 4; ++ks){
    #pragma unroll
    for (int ct = 0; ct < 4; ++ct){
      short8 b0 = *(const short8*)(lds_l + (ct * 16 + m) * WT_STRIDE + ks * 32 + quad * 8);
      acc[ct] = __builtin_amdgcn_mfma_f32_16x16x32_bf16(a0f[ks], b0, acc[ct], 0, 0, 0);
      short8 b1 = *(const short8*)(lds_r + (ct * 16 + m) * WT_STRIDE + ks * 32 + quad * 8);
      acc[ct] = __builtin_amdgcn_mfma_f32_16x16x32_bf16(a1f[ks], b1, acc[ct], 0, 0, 0);
    }
  }
  #pragma unroll
  for (int ct = 0; ct < 4; ++ct){
    int col = ch * 64 + ct * 16 + m;
    float bv = bb[col];
    #pragma unroll
    for (int i = 0; i < 4; ++i){
      int grow = r0 + quad * 4 + i;
      if (grow < n) op[(size_t)grow * 128 + col] = acc[ct][i] + bv;
    }
  }
}

// ---- launcher --------------------------------------------------------------

extern "C" void kernel_launch(void* const* d_in, const int* in_sizes, int n_in,
                              void* d_out, int out_size, void* d_ws, size_t ws_size,
                              hipStream_t stream) {
  const float* x   = (const float*)d_in[0];   // fp32 [N,128]
  const int*   ei  = (const int*)d_in[1];     // int32 [2,E]
  const float* W1l = (const float*)d_in[2];
  const float* b1l = (const float*)d_in[3];
  const float* W1r = (const float*)d_in[4];
  const float* W2l = (const float*)d_in[5];
  const float* b2l = (const float*)d_in[6];
  const float* W2r = (const float*)d_in[7];
  const float* W3l = (const float*)d_in[8];
  const float* b3l = (const float*)d_in[9];
  const float* W3r = (const float*)d_in[10];
  float* out = (float*)d_out;

  const int n = in_sizes[0] / 128;
  const int E = in_sizes[1] / 2;
  const size_t half = (size_t)n * 128;        // elements per output half
  const int WSZ = 128 * 128;

  const int NB = (n + 255) >> 8;              // 256-node buckets (n <= 65536)
  int mean = (E + NB - 1) / NB;
  int CAP = mean + 8 * (int)sqrt((double)mean) + 64;
  CAP = (CAP + 63) & ~63;                     // per-bucket capacity, 8-sigma slack

  size_t off = 0;
  auto carve = [&](size_t bytes) -> void* {
    void* p = (char*)d_ws + off;
    off += (bytes + 255) & ~(size_t)255;
    return p;
  };
  int2*     rowptr2 = (int2*)carve((size_t)n * 8);
  int*      fill    = (int*)carve((size_t)NB * 4);
  int*      esrc    = (int*)carve((size_t)NB * CAP * 4);
  uint16_t* xb      = (uint16_t*)carve(half * 2);            // bf16 copy of x
  uint16_t* wb      = (uint16_t*)carve((size_t)6 * WSZ * 2); // bf16 weights
  uint16_t* x1b     = (uint16_t*)carve(half * 2);            // bf16 x1
  uint16_t* agg     = (uint16_t*)carve(half * 2);            // bf16 agg
  int2*     bins    = (int2*)carve((size_t)NB * CAP * 8);    // pass-1 staging
  (void)ws_size;  // measured ws_size = 256 MiB >> ~50 MB used

  hipMemsetAsync(fill, 0, (size_t)NB * 4, stream);

  int p1blk = (E + 512 * P1_EPT - 1) / (512 * P1_EPT);
  int cblk  = 256;                            // conversion blocks (grid-stride)
  prep_kernel<<<p1blk + cblk, 512, 0, stream>>>(ei, E, NB, CAP, fill, bins, p1blk,
                                                x, W1l, W1r, W2l, W2r, W3l, W3r,
                                                xb, wb, (int)half);
  build_kernel<<<NB, 512, 0, stream>>>(bins, fill, CAP, n, rowptr2, esrc);

  int ablk = (n + 3) / 4;
  int gblk = (n + 63) / 64;
  const uint16_t *Wb1l = wb, *Wb1r = wb + WSZ, *Wb2l = wb + 2 * WSZ,
                 *Wb2r = wb + 3 * WSZ, *Wb3l = wb + 4 * WSZ, *Wb3r = wb + 5 * WSZ;

  // layer 1
  agg_kernel<<<ablk, 256, 0, stream>>>(xb, rowptr2, esrc, agg, n);
  gemm1_kernel<<<dim3(gblk, 2), 256, 0, stream>>>(agg, xb, Wb1l, Wb1r, b1l, x1b, n);

  // shared aggregation of x1, then layers 2+3 (pass in blockIdx.y)
  agg_kernel<<<ablk, 256, 0, stream>>>(x1b, rowptr2, esrc, agg, n);
  gemm23_kernel<<<dim3(gblk, 4), 256, 0, stream>>>(agg, x1b, Wb2l, Wb2r, b2l,
                                                   Wb3l, Wb3r, b3l, out, half, n);
}